// Round 15
// baseline (682.070 us; speedup 1.0000x reference)
//
#include <hip/hip_runtime.h>
#include <hip/hip_bf16.h>

// Problem constants
#define BB 4
#define TT 32
#define LL 64
#define DD 768
#define NHEAD 12
#define DH 64
#define DFF 2048
#define NLAYERS 2
#define ROWS (BB*TT*LL)      // 8192
#define BTN  (BB*TT)         // 128

typedef __attribute__((ext_vector_type(8))) short bf16x8;
typedef __attribute__((ext_vector_type(4))) float f32x4;

// XOR swizzle for [R]x32-short LDS tiles: row r, 16B chunk c (0..3).
__device__ __forceinline__ int swz(int r, int c) {
    return r * 32 + ((c ^ ((r >> 1) & 3)) << 3);
}

// Bijective XCD-aware block remap (m204).
__device__ __forceinline__ int xcd_swizzle(int orig, int nwg) {
    const int q8 = nwg >> 3, r8 = nwg & 7;
    const int xcd = orig & 7, idx = orig >> 3;
    return (xcd < r8 ? xcd * (q8 + 1) : r8 * (q8 + 1) + (xcd - r8) * q8) + idx;
}

__device__ __forceinline__ unsigned pack_bf16(float a, float b) {
    __hip_bfloat16 h0 = __float2bfloat16(a);
    __hip_bfloat16 h1 = __float2bfloat16(b);
    return (unsigned)*reinterpret_cast<unsigned short*>(&h0) |
           ((unsigned)*reinterpret_cast<unsigned short*>(&h1) << 16);
}

__device__ __forceinline__ short bf16s(float a) {
    __hip_bfloat16 h = __float2bfloat16(a);
    return *reinterpret_cast<short*>(&h);
}

// ---------------------------------------------------------------------------
// Fused multi-tensor fp32 -> bf16 cast (7 segments, one launch).
struct CastArgs {
    const float* src[7];
    __hip_bfloat16* dst[7];
    int end[7];
};
__global__ __launch_bounds__(256) void cast_multi_kernel(CastArgs a)
{
    int q = blockIdx.x * 256 + threadIdx.x;
    if (q >= a.end[6]) return;
    int s = 0;
    while (q >= a.end[s]) ++s;
    int local = q - (s ? a.end[s - 1] : 0);
    float4 v = reinterpret_cast<const float4*>(a.src[s])[local];
    ushort4 o;
    __hip_bfloat16 h0 = __float2bfloat16(v.x);
    __hip_bfloat16 h1 = __float2bfloat16(v.y);
    __hip_bfloat16 h2 = __float2bfloat16(v.z);
    __hip_bfloat16 h3 = __float2bfloat16(v.w);
    o.x = *reinterpret_cast<unsigned short*>(&h0);
    o.y = *reinterpret_cast<unsigned short*>(&h1);
    o.z = *reinterpret_cast<unsigned short*>(&h2);
    o.w = *reinterpret_cast<unsigned short*>(&h3);
    reinterpret_cast<ushort4*>(a.dst[s])[local] = o;
}

// ---------------------------------------------------------------------------
// Fused: teb = bf16(te), edu_b = bf16(mean over L of te). One read of te.
__global__ __launch_bounds__(256) void te_prep_kernel(
    const float* __restrict__ te, __hip_bfloat16* __restrict__ teb,
    __hip_bfloat16* __restrict__ edu_b)
{
    int idx = blockIdx.x * 256 + threadIdx.x;
    int bt = idx / DD;
    int d  = idx - bt * DD;
    const float* p = te + ((size_t)bt * LL) * DD + d;
    __hip_bfloat16* q = teb + ((size_t)bt * LL) * DD + d;
    float s = 0.f;
#pragma unroll
    for (int l = 0; l < LL; ++l) {
        float v = p[(size_t)l * DD];
        s += v;
        q[(size_t)l * DD] = __float2bfloat16(v);
    }
    edu_b[idx] = __float2bfloat16(s * (1.0f / (float)LL));
}

// ---------------------------------------------------------------------------
// bf16 MFMA GEMM, 128x128 tile, BK=32, 256 thr (4 waves 2x2).
// A-frags read DIRECT from global (16 full 64B lines/wave, L2-hot via
// bm-major XCD chunks); B staged through double-buffered XOR-swizzled LDS
// (reg-staged, 1 barrier/K-step). Rationale (R13 PMC): LDS pipe was the
// bound (48KB/K-step = 375cyc vs 77cyc MFMA -> 21% MfmaUtil). B-only LDS
// = 24KB/K-step -> ~40% ceiling.
// NOTE (R12): 256-row tile regressed (128 acc VGPRs, occupancy 7.8%).
// NOTE (R14): m97-style global_load_lds 2-barrier regressed (no overlap).
template<int OUT_BF16, int RELU, int QKV>
__global__ __launch_bounds__(256) void gemm_bf16_kernel(
    const __hip_bfloat16* __restrict__ A,
    const __hip_bfloat16* __restrict__ B,
    const float* __restrict__ bias,
    void* __restrict__ Cout,
    __hip_bfloat16* __restrict__ Vout,
    int M, int N, int K, int ldC)
{
    __shared__ short lB[2][4096];
    const int tid  = threadIdx.x;
    const int lane = tid & 63;
    const int w    = tid >> 6;
    const int wr   = w >> 1, wc = w & 1;

    const int nbx = gridDim.x;
    const int wg = xcd_swizzle(blockIdx.y * nbx + blockIdx.x, nbx * gridDim.y);
    const int bm = (wg / nbx) * 128;
    const int bn = (wg % nbx) * 128;

    const int sr  = tid >> 2;
    const int cw  = tid & 3;
    const int sco = cw << 3;

    const int wo0 = swz(sr, cw);
    const int wo1 = swz(sr + 64, cw);
    int roB[4];
#pragma unroll
    for (int n = 0; n < 4; ++n)
        roB[n] = swz(wc * 64 + n * 16 + (lane & 15), lane >> 4);

    const short* Ag = reinterpret_cast<const short*>(A);
    const short* Bg = reinterpret_cast<const short*>(B);

    // per-lane A-frag base pointers (row = bm + wr*64 + m*16 + lo, col = hi*8)
    const int lo = lane & 15, hi = lane >> 4;
    const short* Arow[4];
#pragma unroll
    for (int m = 0; m < 4; ++m)
        Arow[m] = Ag + (size_t)(bm + wr * 64 + m * 16 + lo) * K + hi * 8;

    f32x4 acc[4][4] = {};

    // prologue: B tile 0 -> regs -> LDS buf0
    bf16x8 rb0 = *reinterpret_cast<const bf16x8*>(Bg + (size_t)(bn + sr) * K + sco);
    bf16x8 rb1 = *reinterpret_cast<const bf16x8*>(Bg + (size_t)(bn + 64 + sr) * K + sco);
    *reinterpret_cast<bf16x8*>(&lB[0][wo0]) = rb0;
    *reinterpret_cast<bf16x8*>(&lB[0][wo1]) = rb1;
    __syncthreads();

    const int NT = K >> 5;
    int cur = 0;
    for (int t = 0; t < NT; ++t) {
        const int k0 = t << 5;
        // A-frags for this tile: issue first (oldest in flight)
        bf16x8 af[4];
#pragma unroll
        for (int m = 0; m < 4; ++m)
            af[m] = *reinterpret_cast<const bf16x8*>(Arow[m] + k0);

        const bool nx = (t + 1 < NT);
        if (nx) {  // B staging loads for next tile; consumed after MFMA
            const int kn = k0 + 32;
            rb0 = *reinterpret_cast<const bf16x8*>(Bg + (size_t)(bn + sr) * K + kn + sco);
            rb1 = *reinterpret_cast<const bf16x8*>(Bg + (size_t)(bn + 64 + sr) * K + kn + sco);
        }

        bf16x8 bfr[4];
#pragma unroll
        for (int n = 0; n < 4; ++n)
            bfr[n] = *reinterpret_cast<const bf16x8*>(&lB[cur][roB[n]]);
#pragma unroll
        for (int m = 0; m < 4; ++m)
#pragma unroll
            for (int n = 0; n < 4; ++n)
                acc[m][n] = __builtin_amdgcn_mfma_f32_16x16x32_bf16(
                    af[m], bfr[n], acc[m][n], 0, 0, 0);

        if (nx) {
            *reinterpret_cast<bf16x8*>(&lB[cur ^ 1][wo0]) = rb0;
            *reinterpret_cast<bf16x8*>(&lB[cur ^ 1][wo1]) = rb1;
        }
        __syncthreads();
        cur ^= 1;
    }

    const int crow = (lane >> 4) * 4;
    const int ccol = lane & 15;
#pragma unroll
    for (int n = 0; n < 4; ++n) {
        const int col = bn + wc * 64 + n * 16 + ccol;
        const float bv = bias ? bias[col] : 0.f;
        if (QKV && col >= 1536) {
            const int hh = (col - 1536) >> 6;
            const int d  = (col - 1536) & 63;
#pragma unroll
            for (int m = 0; m < 4; ++m) {
                const int row0 = bm + wr * 64 + m * 16 + crow;
#pragma unroll
                for (int j = 0; j < 4; ++j) {
                    const int row = row0 + j;
                    const int ni = row >> 6, ll = row & 63;
                    Vout[(((size_t)ni * NHEAD + hh) << 12) + (d << 6) + ll] =
                        __float2bfloat16(acc[m][n][j] + bv);
                }
            }
        } else {
#pragma unroll
            for (int m = 0; m < 4; ++m) {
                const int row0 = bm + wr * 64 + m * 16 + crow;
#pragma unroll
                for (int j = 0; j < 4; ++j) {
                    float v = acc[m][n][j] + bv;
                    if (RELU) v = fmaxf(v, 0.f);
                    if (OUT_BF16)
                        reinterpret_cast<__hip_bfloat16*>(Cout)[(size_t)(row0 + j) * ldC + col] =
                            __float2bfloat16(v);
                    else
                        reinterpret_cast<float*>(Cout)[(size_t)(row0 + j) * ldC + col] = v;
                }
            }
        }
    }
}

// ---------------------------------------------------------------------------
// MFMA attention: one wave per (n,h). qk: (8192,1536) bf16 Q|K rows;
// vt: (128,12,64,64) bf16 V^T; out: (8192,768) bf16.
__global__ __launch_bounds__(64) void attn_mfma_kernel(
    const __hip_bfloat16* __restrict__ qk,
    const __hip_bfloat16* __restrict__ vt,
    __hip_bfloat16* __restrict__ out)
{
    const int n = blockIdx.x, h = blockIdx.y;
    const int lane = threadIdx.x;
    const int lo = lane & 15, hi = lane >> 4;
    __shared__ short pl[64 * 72];

    const short* qg = reinterpret_cast<const short*>(qk) + (size_t)(n * 64) * 1536 + h * 64;

    f32x4 acc[4][4] = {};
#pragma unroll
    for (int ks = 0; ks < 2; ++ks) {
        const int kc = ks * 32 + hi * 8;
        bf16x8 af[4], bk[4];
#pragma unroll
        for (int m = 0; m < 4; ++m)
            af[m] = *reinterpret_cast<const bf16x8*>(qg + (size_t)(m * 16 + lo) * 1536 + kc);
#pragma unroll
        for (int nn = 0; nn < 4; ++nn)
            bk[nn] = *reinterpret_cast<const bf16x8*>(qg + 768 + (size_t)(nn * 16 + lo) * 1536 + kc);
#pragma unroll
        for (int m = 0; m < 4; ++m)
#pragma unroll
            for (int nn = 0; nn < 4; ++nn)
                acc[m][nn] = __builtin_amdgcn_mfma_f32_16x16x32_bf16(
                    af[m], bk[nn], acc[m][nn], 0, 0, 0);
    }

#pragma unroll
    for (int m = 0; m < 4; ++m) {
#pragma unroll
        for (int j = 0; j < 4; ++j) {
            float s0 = acc[m][0][j] * 0.125f;
            float s1 = acc[m][1][j] * 0.125f;
            float s2 = acc[m][2][j] * 0.125f;
            float s3 = acc[m][3][j] * 0.125f;
            float mx = fmaxf(fmaxf(s0, s1), fmaxf(s2, s3));
            mx = fmaxf(mx, __shfl_xor(mx, 1));
            mx = fmaxf(mx, __shfl_xor(mx, 2));
            mx = fmaxf(mx, __shfl_xor(mx, 4));
            mx = fmaxf(mx, __shfl_xor(mx, 8));
            float e0 = __expf(s0 - mx), e1 = __expf(s1 - mx);
            float e2 = __expf(s2 - mx), e3 = __expf(s3 - mx);
            float sm = e0 + e1 + e2 + e3;
            sm += __shfl_xor(sm, 1);
            sm += __shfl_xor(sm, 2);
            sm += __shfl_xor(sm, 4);
            sm += __shfl_xor(sm, 8);
            const float inv = 1.0f / sm;
            short* pr = &pl[(m * 16 + hi * 4 + j) * 72 + lo];
            pr[0]  = bf16s(e0 * inv);
            pr[16] = bf16s(e1 * inv);
            pr[32] = bf16s(e2 * inv);
            pr[48] = bf16s(e3 * inv);
        }
    }
    __syncthreads();

    const short* vg = reinterpret_cast<const short*>(vt) + ((size_t)(n * NHEAD + h) << 12);
    f32x4 o[4][4] = {};
#pragma unroll
    for (int ks = 0; ks < 2; ++ks) {
        const int kc = ks * 32 + hi * 8;
        bf16x8 pa[4], bv[4];
#pragma unroll
        for (int m = 0; m < 4; ++m)
            pa[m] = *reinterpret_cast<const bf16x8*>(&pl[(m * 16 + lo) * 72 + kc]);
#pragma unroll
        for (int nn = 0; nn < 4; ++nn)
            bv[nn] = *reinterpret_cast<const bf16x8*>(vg + (nn * 16 + lo) * 64 + kc);
#pragma unroll
        for (int m = 0; m < 4; ++m)
#pragma unroll
            for (int nn = 0; nn < 4; ++nn)
                o[m][nn] = __builtin_amdgcn_mfma_f32_16x16x32_bf16(
                    pa[m], bv[nn], o[m][nn], 0, 0, 0);
    }

#pragma unroll
    for (int m = 0; m < 4; ++m)
#pragma unroll
        for (int nn = 0; nn < 4; ++nn)
#pragma unroll
            for (int j = 0; j < 4; ++j)
                out[(size_t)(n * 64 + m * 16 + hi * 4 + j) * DD + h * 64 + nn * 16 + lo] =
                    __float2bfloat16(o[m][nn][j]);
}

// ---------------------------------------------------------------------------
// SAUTE part 1 (MFMA): P[row][u] = mask * (tok[row,:].v[b,u,:]).
__global__ __launch_bounds__(64) void saute_p_mfma_kernel(
    const __hip_bfloat16* __restrict__ Xb,
    const __hip_bfloat16* __restrict__ KV,
    const int* __restrict__ spk,
    __hip_bfloat16* __restrict__ P)
{
    const int lane = threadIdx.x;
    const int lo = lane & 15, hi = lane >> 4;
    const int row0 = blockIdx.x * 64;
    const int bt = row0 >> 6;
    const int b  = bt >> 5, t = bt & 31;

    const short* Ag = reinterpret_cast<const short*>(Xb) + (size_t)row0 * DD;
    const short* Bg = reinterpret_cast<const short*>(KV) + (size_t)(b * TT) * 1536 + 768;

    f32x4 acc[4][2] = {};
    for (int ks = 0; ks < 24; ++ks) {
        const int kc = ks * 32 + hi * 8;
        bf16x8 af[4], bv[2];
#pragma unroll
        for (int m = 0; m < 4; ++m)
            af[m] = *reinterpret_cast<const bf16x8*>(Ag + (size_t)(m * 16 + lo) * DD + kc);
#pragma unroll
        for (int nn = 0; nn < 2; ++nn)
            bv[nn] = *reinterpret_cast<const bf16x8*>(Bg + (size_t)(nn * 16 + lo) * 1536 + kc);
#pragma unroll
        for (int m = 0; m < 4; ++m)
#pragma unroll
            for (int nn = 0; nn < 2; ++nn)
                acc[m][nn] = __builtin_amdgcn_mfma_f32_16x16x32_bf16(
                    af[m], bv[nn], acc[m][nn], 0, 0, 0);
    }

    const int st = spk[bt];
#pragma unroll
    for (int nn = 0; nn < 2; ++nn) {
        const int u = nn * 16 + lo;
        const bool mk = (u <= t) && (spk[b * TT + u] == st);
#pragma unroll
        for (int m = 0; m < 4; ++m)
#pragma unroll
            for (int j = 0; j < 4; ++j) {
                const int row = row0 + m * 16 + hi * 4 + j;
                P[(size_t)row * 32 + u] =
                    mk ? __float2bfloat16(acc[m][nn][j]) : __float2bfloat16(0.f);
            }
    }
}

// ---------------------------------------------------------------------------
// SAUTE part 2: ctx = tok + P @ k, in place on bf16 Xb.
__global__ __launch_bounds__(256) void saute_ctx_kernel(
    __hip_bfloat16* __restrict__ Xb,
    const __hip_bfloat16* __restrict__ KV,
    const __hip_bfloat16* __restrict__ P)
{
    __shared__ unsigned kls[32 * 384];
    __shared__ float pls[8 * 32];
    const int row0 = blockIdx.x * 8;
    const int b = row0 >> 11;
    const int tid = threadIdx.x;

    const unsigned* k2 = reinterpret_cast<const unsigned*>(KV) + (size_t)(b * TT) * 768;
    for (int i = tid; i < 32 * 384; i += 256) {
        int u = i / 384, j = i - u * 384;
        kls[i] = k2[u * 768 + j];
    }
    pls[tid] = __bfloat162float(P[(size_t)row0 * 32 + tid]);
    __syncthreads();

    const int r = tid >> 5;
    const int l32 = tid & 31;
    unsigned* xrow = reinterpret_cast<unsigned*>(Xb + (size_t)(row0 + r) * DD);

    float2 acc[12];
#pragma unroll
    for (int c = 0; c < 12; ++c) {
        unsigned pk = xrow[l32 + 32 * c];
        acc[c].x = __uint_as_float(pk << 16);
        acc[c].y = __uint_as_float(pk & 0xffff0000u);
    }
    for (int u = 0; u < 32; ++u) {
        const float pv = pls[r * 32 + u];
        const unsigned* kr = &kls[u * 384];
#pragma unroll
        for (int c = 0; c < 12; ++c) {
            unsigned pk = kr[l32 + 32 * c];
            acc[c].x = fmaf(pv, __uint_as_float(pk << 16),          acc[c].x);
            acc[c].y = fmaf(pv, __uint_as_float(pk & 0xffff0000u), acc[c].y);
        }
    }
#pragma unroll
    for (int c = 0; c < 12; ++c)
        xrow[l32 + 32 * c] = pack_bf16(acc[c].x, acc[c].y);
}

// ---------------------------------------------------------------------------
// LayerNorm over bf16 residual: xb = bf16(LN(xb + y)); FINAL also writes fp32.
template<int FINAL>
__global__ __launch_bounds__(192) void add_ln_kernel(
    __hip_bfloat16* __restrict__ xb, const __hip_bfloat16* __restrict__ y,
    const float* __restrict__ g, const float* __restrict__ bb,
    float* __restrict__ xf)
{
    const int row = blockIdx.x;
    const int tid = threadIdx.x;
    __shared__ float red[3];
    __shared__ float stat[2];
    const size_t base = (size_t)row * DD + tid * 4;

    uint2 xv = *reinterpret_cast<const uint2*>(xb + base);
    uint2 yv = *reinterpret_cast<const uint2*>(y + base);
    float v[4];
    v[0] = __uint_as_float(xv.x << 16)         + __uint_as_float(yv.x << 16);
    v[1] = __uint_as_float(xv.x & 0xffff0000u) + __uint_as_float(yv.x & 0xffff0000u);
    v[2] = __uint_as_float(xv.y << 16)         + __uint_as_float(yv.y << 16);
    v[3] = __uint_as_float(xv.y & 0xffff0000u) + __uint_as_float(yv.y & 0xffff0000u);

    float s = v[0] + v[1] + v[2] + v[3];
#pragma unroll
    for (int off = 32; off > 0; off >>= 1) s += __shfl_down(s, off);
    if ((tid & 63) == 0) red[tid >> 6] = s;
    __syncthreads();
    if (tid == 0) stat[0] = (red[0] + red[1] + red[2]) * (1.0f / (float)DD);
    __syncthreads();
    const float mu = stat[0];

    float d[4];
    float q = 0.f;
#pragma unroll
    for (int i = 0; i < 4; ++i) { d[i] = v[i] - mu; q += d[i] * d[i]; }
    __syncthreads();
#pragma unroll
    for (int off = 32; off > 0; off >>= 1) q += __shfl_down(q, off);
    if ((tid & 63) == 0) red[tid >> 6] = q;
    __syncthreads();
    if (tid == 0) stat[1] = (red[0] + red[1] + red[2]) * (1.0f / (float)DD);
    __syncthreads();
    const float rstd = rsqrtf(stat[1] + 1e-5f);

    float o[4];
#pragma unroll
    for (int i = 0; i < 4; ++i)
        o[i] = d[i] * rstd * g[tid * 4 + i] + bb[tid * 4 + i];

    if (FINAL) {
        float4 f4 = make_float4(o[0], o[1], o[2], o[3]);
        *reinterpret_cast<float4*>(xf + base) = f4;
    } else {
        uint2 ov;
        ov.x = pack_bf16(o[0], o[1]);
        ov.y = pack_bf16(o[2], o[3]);
        *reinterpret_cast<uint2*>(xb + base) = ov;
    }
}

// ---------------------------------------------------------------------------
extern "C" void kernel_launch(void* const* d_in, const int* in_sizes, int n_in,
                              void* d_out, int out_size, void* d_ws, size_t ws_size,
                              hipStream_t stream) {
    (void)in_sizes; (void)n_in; (void)out_size; (void)ws_size;
    const float* te  = (const float*)d_in[0];
    const int*   spk = (const int*)  d_in[1];
    const float* Wq  = (const float*)d_in[2];
    const float* Wk  = (const float*)d_in[3];
    const float* Wv  = (const float*)d_in[4];
    const float* ipw = (const float*)d_in[5];
    const float* ipb = (const float*)d_in[6];
    const float* ow  = (const float*)d_in[7];
    const float* ob  = (const float*)d_in[8];
    const float* g1  = (const float*)d_in[9];
    const float* b1  = (const float*)d_in[10];
    const float* f1w = (const float*)d_in[11];
    const float* f1b = (const float*)d_in[12];
    const float* f2w = (const float*)d_in[13];
    const float* f2b = (const float*)d_in[14];
    const float* g2  = (const float*)d_in[15];
    const float* b2  = (const float*)d_in[16];

    float* Xout = (float*)d_out;

    // ws layout (bf16, all byte offsets multiples of 16)
    __hip_bfloat16* wsb   = (__hip_bfloat16*)d_ws;
    __hip_bfloat16* Wq_b  = wsb;                               //   589,824
    __hip_bfloat16* ipw_b = Wq_b  + 589824;                    // 3,538,944
    __hip_bfloat16* ow_b  = ipw_b + 3538944;                   // 1,179,648
    __hip_bfloat16* f1w_b = ow_b  + 1179648;                   // 3,145,728
    __hip_bfloat16* f2w_b = f1w_b + 3145728;                   // 3,145,728
    __hip_bfloat16* Xb    = f2w_b + 3145728;                   // 6,291,456 (bf16 residual)
    __hip_bfloat16* SCR   = Xb    + 6291456;                   // 18,874,368 combined region:
                                                               //   q|k (ld1536) + Vt; ff1 hidden
                                                               //   (ld2048) overruns into Vt AFTER
                                                               //   attn consumed it (safe);
                                                               //   Wkv_b aliases base pre-layer.
    __hip_bfloat16* Vt    = SCR   + 12582912;
    __hip_bfloat16* Wkv_b = SCR;                               // pre-layer alias
    __hip_bfloat16* Ab    = SCR   + 18874368;                  // 6,291,456
    __hip_bfloat16* Yb    = Ab    + 6291456;                   // 6,291,456
    __hip_bfloat16* KV    = Yb    + 6291456;                   // 196,608
    __hip_bfloat16* Pb    = KV    + 196608;                    // 262,144
    __hip_bfloat16* edu_b = Pb    + 262144;                    // 98,304

    // 1. te prep
    te_prep_kernel<<<(BTN * DD) / 256, 256, 0, stream>>>(te, Ab, edu_b);

    // 2. all weight casts in one launch
    CastArgs ca;
    ca.src[0] = Wq;  ca.dst[0] = Wq_b;
    ca.src[1] = ipw; ca.dst[1] = ipw_b;
    ca.src[2] = ow;  ca.dst[2] = ow_b;
    ca.src[3] = f1w; ca.dst[3] = f1w_b;
    ca.src[4] = f2w; ca.dst[4] = f2w_b;
    ca.src[5] = Wk;  ca.dst[5] = Wkv_b;
    ca.src[6] = Wv;  ca.dst[6] = Wkv_b + 589824;
    int quads[7] = {589824/4, 3538944/4, 1179648/4, 3145728/4, 3145728/4, 589824/4, 589824/4};
    int acc = 0;
    for (int i = 0; i < 7; ++i) { acc += quads[i]; ca.end[i] = acc; }
    cast_multi_kernel<<<(acc + 255) / 256, 256, 0, stream>>>(ca);

    // 3. k|v projection: KV = edu_b @ (Wk|Wv)^T
    gemm_bf16_kernel<1,0,0><<<dim3(1536/128, 1), 256, 0, stream>>>(
        edu_b, Wkv_b, nullptr, KV, nullptr, BTN, 1536, DD, 1536);

    // 4. tok = TE @ Wq^T  (bf16 out -> Xb)
    gemm_bf16_kernel<1,0,0><<<dim3(DD/128, ROWS/128), 256, 0, stream>>>(
        Ab, Wq_b, nullptr, Xb, nullptr, ROWS, DD, DD, DD);

    // 5. SAUTE
    saute_p_mfma_kernel<<<ROWS/64, 64, 0, stream>>>(Xb, KV, spk, Pb);
    saute_ctx_kernel<<<ROWS/8, 256, 0, stream>>>(Xb, KV, Pb);

    // 6. transformer layers
    for (int l = 0; l < NLAYERS; ++l) {
        const __hip_bfloat16* ipw_l = ipw_b + (size_t)l * 3 * DD * DD;
        const __hip_bfloat16* ow_l  = ow_b  + (size_t)l * DD * DD;
        const __hip_bfloat16* f1w_l = f1w_b + (size_t)l * DFF * DD;
        const __hip_bfloat16* f2w_l = f2w_b + (size_t)l * DD * DFF;

        // qkv: Q|K -> SCR (ld 1536), V -> Vt (transposed per head)
        gemm_bf16_kernel<1,0,1><<<dim3(3*DD/128, ROWS/128), 256, 0, stream>>>(
            Xb, ipw_l, ipb + (size_t)l * 3 * DD, SCR, Vt, ROWS, 3*DD, DD, 1536);
        // attention -> Ab
        attn_mfma_kernel<<<dim3(BTN, NHEAD), 64, 0, stream>>>(SCR, Vt, Ab);
        // out proj -> Yb
        gemm_bf16_kernel<1,0,0><<<dim3(DD/128, ROWS/128), 256, 0, stream>>>(
            Ab, ow_l, ob + (size_t)l * DD, Yb, nullptr, ROWS, DD, DD, DD);
        // Xb = LN(Xb + Yb)
        add_ln_kernel<0><<<ROWS, 192, 0, stream>>>(
            Xb, Yb, g1 + (size_t)l * DD, b1 + (size_t)l * DD, nullptr);
        // H = relu(Xb @ ff1^T + b) -> SCR (bf16, ld 2048)
        gemm_bf16_kernel<1,1,0><<<dim3(DFF/128, ROWS/128), 256, 0, stream>>>(
            Xb, f1w_l, f1b + (size_t)l * DFF, SCR, nullptr, ROWS, DFF, DD, DFF);
        // P = H @ ff2^T + b -> Yb, K=2048
        gemm_bf16_kernel<1,0,0><<<dim3(DD/128, ROWS/128), 256, 0, stream>>>(
            SCR, f2w_l, f2b + (size_t)l * DD, Yb, nullptr, ROWS, DD, DFF, DD);
        // Xb = LN(Xb + Yb); final layer writes fp32 d_out
        if (l == NLAYERS - 1)
            add_ln_kernel<1><<<ROWS, 192, 0, stream>>>(
                Xb, Yb, g2 + (size_t)l * DD, b2 + (size_t)l * DD, Xout);
        else
            add_ln_kernel<0><<<ROWS, 192, 0, stream>>>(
                Xb, Yb, g2 + (size_t)l * DD, b2 + (size_t)l * DD, nullptr);
    }
}

// Round 16
// 604.106 us; speedup vs baseline: 1.1291x; 1.1291x over previous
//
#include <hip/hip_runtime.h>
#include <hip/hip_bf16.h>

// Problem constants
#define BB 4
#define TT 32
#define LL 64
#define DD 768
#define NHEAD 12
#define DH 64
#define DFF 2048
#define NLAYERS 2
#define ROWS (BB*TT*LL)      // 8192
#define BTN  (BB*TT)         // 128

typedef __attribute__((ext_vector_type(8))) short bf16x8;
typedef __attribute__((ext_vector_type(4))) float f32x4;

#define GLOAD_LDS16(g, l) __builtin_amdgcn_global_load_lds( \
    (const __attribute__((address_space(1))) void*)(g),     \
    (__attribute__((address_space(3))) void*)(l), 16, 0, 0)

// XOR swizzle for [R]x32-short LDS tiles: row r, 16B chunk c (0..3).
__device__ __forceinline__ int swz(int r, int c) {
    return r * 32 + ((c ^ ((r >> 1) & 3)) << 3);
}

// Bijective XCD-aware block remap (m204).
__device__ __forceinline__ int xcd_swizzle(int orig, int nwg) {
    const int q8 = nwg >> 3, r8 = nwg & 7;
    const int xcd = orig & 7, idx = orig >> 3;
    return (xcd < r8 ? xcd * (q8 + 1) : r8 * (q8 + 1) + (xcd - r8) * q8) + idx;
}

__device__ __forceinline__ unsigned pack_bf16(float a, float b) {
    __hip_bfloat16 h0 = __float2bfloat16(a);
    __hip_bfloat16 h1 = __float2bfloat16(b);
    return (unsigned)*reinterpret_cast<unsigned short*>(&h0) |
           ((unsigned)*reinterpret_cast<unsigned short*>(&h1) << 16);
}

__device__ __forceinline__ short bf16s(float a) {
    __hip_bfloat16 h = __float2bfloat16(a);
    return *reinterpret_cast<short*>(&h);
}

// ---------------------------------------------------------------------------
// Fused multi-tensor fp32 -> bf16 cast (7 segments, one launch).
struct CastArgs {
    const float* src[7];
    __hip_bfloat16* dst[7];
    int end[7];
};
__global__ __launch_bounds__(256) void cast_multi_kernel(CastArgs a)
{
    int q = blockIdx.x * 256 + threadIdx.x;
    if (q >= a.end[6]) return;
    int s = 0;
    while (q >= a.end[s]) ++s;
    int local = q - (s ? a.end[s - 1] : 0);
    float4 v = reinterpret_cast<const float4*>(a.src[s])[local];
    ushort4 o;
    __hip_bfloat16 h0 = __float2bfloat16(v.x);
    __hip_bfloat16 h1 = __float2bfloat16(v.y);
    __hip_bfloat16 h2 = __float2bfloat16(v.z);
    __hip_bfloat16 h3 = __float2bfloat16(v.w);
    o.x = *reinterpret_cast<unsigned short*>(&h0);
    o.y = *reinterpret_cast<unsigned short*>(&h1);
    o.z = *reinterpret_cast<unsigned short*>(&h2);
    o.w = *reinterpret_cast<unsigned short*>(&h3);
    reinterpret_cast<ushort4*>(a.dst[s])[local] = o;
}

// ---------------------------------------------------------------------------
// Fused: teb = bf16(te), edu_b = bf16(mean over L of te). One read of te.
__global__ __launch_bounds__(256) void te_prep_kernel(
    const float* __restrict__ te, __hip_bfloat16* __restrict__ teb,
    __hip_bfloat16* __restrict__ edu_b)
{
    int idx = blockIdx.x * 256 + threadIdx.x;
    int bt = idx / DD;
    int d  = idx - bt * DD;
    const float* p = te + ((size_t)bt * LL) * DD + d;
    __hip_bfloat16* q = teb + ((size_t)bt * LL) * DD + d;
    float s = 0.f;
#pragma unroll
    for (int l = 0; l < LL; ++l) {
        float v = p[(size_t)l * DD];
        s += v;
        q[(size_t)l * DD] = __float2bfloat16(v);
    }
    edu_b[idx] = __float2bfloat16(s * (1.0f / (float)LL));
}

// ---------------------------------------------------------------------------
// bf16 MFMA GEMM, 128x128 tile, BK=32 (kv / tok / out-proj / ff2).
// Reg-staged double-buffered LDS (R13-proven: keeps global latency one full
// iteration ahead), XOR-swizzled, XCD-swizzled. Single instantiation <1,0,0>.
// NOTE (R15): direct-from-global A-frags regressed (in-iteration latency).
template<int OUT_BF16, int RELU, int QKV>
__global__ __launch_bounds__(256) void gemm_bf16_kernel(
    const __hip_bfloat16* __restrict__ A,
    const __hip_bfloat16* __restrict__ B,
    const float* __restrict__ bias,
    void* __restrict__ Cout,
    __hip_bfloat16* __restrict__ Vout,
    int M, int N, int K, int ldC)
{
    __shared__ short lA[2][4096];
    __shared__ short lB[2][4096];
    const int tid  = threadIdx.x;
    const int lane = tid & 63;
    const int w    = tid >> 6;
    const int wr   = w >> 1, wc = w & 1;

    const int nbx = gridDim.x;
    const int wg = xcd_swizzle(blockIdx.y * nbx + blockIdx.x, nbx * gridDim.y);
    const int bm = (wg / nbx) * 128;
    const int bn = (wg % nbx) * 128;

    const int sr  = tid >> 2;
    const int cw  = tid & 3;
    const int sco = cw << 3;

    const int wo0 = swz(sr, cw);
    const int wo1 = swz(sr + 64, cw);
    int roA[4], roB[4];
#pragma unroll
    for (int m = 0; m < 4; ++m)
        roA[m] = swz(wr * 64 + m * 16 + (lane & 15), lane >> 4);
#pragma unroll
    for (int n = 0; n < 4; ++n)
        roB[n] = swz(wc * 64 + n * 16 + (lane & 15), lane >> 4);

    const short* Ag = reinterpret_cast<const short*>(A);
    const short* Bg = reinterpret_cast<const short*>(B);

    f32x4 acc[4][4] = {};

    bf16x8 ra0 = *reinterpret_cast<const bf16x8*>(Ag + (size_t)(bm + sr) * K + sco);
    bf16x8 ra1 = *reinterpret_cast<const bf16x8*>(Ag + (size_t)(bm + 64 + sr) * K + sco);
    bf16x8 rb0 = *reinterpret_cast<const bf16x8*>(Bg + (size_t)(bn + sr) * K + sco);
    bf16x8 rb1 = *reinterpret_cast<const bf16x8*>(Bg + (size_t)(bn + 64 + sr) * K + sco);
    *reinterpret_cast<bf16x8*>(&lA[0][wo0]) = ra0;
    *reinterpret_cast<bf16x8*>(&lA[0][wo1]) = ra1;
    *reinterpret_cast<bf16x8*>(&lB[0][wo0]) = rb0;
    *reinterpret_cast<bf16x8*>(&lB[0][wo1]) = rb1;
    __syncthreads();

    const int NT = K >> 5;
    int cur = 0;
    for (int t = 0; t < NT; ++t) {
        const bool nx = (t + 1 < NT);
        if (nx) {
            const int kn = (t + 1) << 5;
            ra0 = *reinterpret_cast<const bf16x8*>(Ag + (size_t)(bm + sr) * K + kn + sco);
            ra1 = *reinterpret_cast<const bf16x8*>(Ag + (size_t)(bm + 64 + sr) * K + kn + sco);
            rb0 = *reinterpret_cast<const bf16x8*>(Bg + (size_t)(bn + sr) * K + kn + sco);
            rb1 = *reinterpret_cast<const bf16x8*>(Bg + (size_t)(bn + 64 + sr) * K + kn + sco);
        }

        bf16x8 af[4], bfr[4];
#pragma unroll
        for (int m = 0; m < 4; ++m)
            af[m] = *reinterpret_cast<const bf16x8*>(&lA[cur][roA[m]]);
#pragma unroll
        for (int n = 0; n < 4; ++n)
            bfr[n] = *reinterpret_cast<const bf16x8*>(&lB[cur][roB[n]]);
#pragma unroll
        for (int m = 0; m < 4; ++m)
#pragma unroll
            for (int n = 0; n < 4; ++n)
                acc[m][n] = __builtin_amdgcn_mfma_f32_16x16x32_bf16(
                    af[m], bfr[n], acc[m][n], 0, 0, 0);

        if (nx) {
            *reinterpret_cast<bf16x8*>(&lA[cur ^ 1][wo0]) = ra0;
            *reinterpret_cast<bf16x8*>(&lA[cur ^ 1][wo1]) = ra1;
            *reinterpret_cast<bf16x8*>(&lB[cur ^ 1][wo0]) = rb0;
            *reinterpret_cast<bf16x8*>(&lB[cur ^ 1][wo1]) = rb1;
        }
        __syncthreads();
        cur ^= 1;
    }

    const int crow = (lane >> 4) * 4;
    const int ccol = lane & 15;
#pragma unroll
    for (int n = 0; n < 4; ++n) {
        const int col = bn + wc * 64 + n * 16 + ccol;
        const float bv = bias ? bias[col] : 0.f;
#pragma unroll
        for (int m = 0; m < 4; ++m) {
            const int row0 = bm + wr * 64 + m * 16 + crow;
#pragma unroll
            for (int j = 0; j < 4; ++j) {
                float v = acc[m][n][j] + bv;
                if (RELU) v = fmaxf(v, 0.f);
                if (OUT_BF16)
                    reinterpret_cast<__hip_bfloat16*>(Cout)[(size_t)(row0 + j) * ldC + col] =
                        __float2bfloat16(v);
                else
                    reinterpret_cast<float*>(Cout)[(size_t)(row0 + j) * ldC + col] = v;
            }
        }
    }
}

// ---------------------------------------------------------------------------
// bf16 MFMA GEMM, 256x128 tile, BK=32, global_load_lds staging (qkv / ff1).
// Rationale: R13's 21% MfmaUtil = LDS-pipe bound (48KB/K-step vs 77 MFMA
// cyc). 128x64 wave tile -> 12 LDS reads per 32 MFMA (0.375 vs 0.5) and
// DMA staging (no reg round-trip, no staging VGPRs -> ~3 waves/SIMD, fixes
// R12's occupancy kill). 32 MFMA/K-step amortizes the vmcnt(0) drain that
// killed R14. Single 2-barrier buffer; swizzled-source (R14-proven).
// flags: bit1 = relu, bit2 = qkv split (V -> Vout^T). Out always bf16.
__global__ __launch_bounds__(256) void gemm_256_kernel(
    const __hip_bfloat16* __restrict__ A,
    const __hip_bfloat16* __restrict__ B,
    const float* __restrict__ bias,
    __hip_bfloat16* __restrict__ Cout,
    __hip_bfloat16* __restrict__ Vout,
    int M, int N, int K, int ldC, int flags)
{
    __shared__ short lA[8192];   // 256 x 32
    __shared__ short lB[4096];   // 128 x 32
    const int tid  = threadIdx.x;
    const int lane = tid & 63;
    const int w    = tid >> 6;
    const int wr   = w >> 1, wc = w & 1;

    const int nbx = gridDim.x;
    const int wg = xcd_swizzle(blockIdx.y * nbx + blockIdx.x, nbx * gridDim.y);
    const int bm = (wg / nbx) * 256;
    const int bn = (wg % nbx) * 128;

    // staging: A = 16 segs (wave w: 4w..4w+3), B = 8 segs (wave w: 2w..2w+1).
    // lane -> row seg*16+(lane>>2), chunk lane&3; source col pre-swizzled.
    const int lrow = lane >> 2;
    const int lchk = lane & 3;
    int rowA[4], scA[4];
    short* dstA[4];
#pragma unroll
    for (int i = 0; i < 4; ++i) {
        const int seg = w * 4 + i;
        rowA[i] = seg * 16 + lrow;
        scA[i]  = (lchk ^ ((rowA[i] >> 1) & 3)) << 3;
        dstA[i] = &lA[seg * 512];
    }
    int rowB[2], scB[2];
    short* dstB[2];
#pragma unroll
    for (int i = 0; i < 2; ++i) {
        const int seg = w * 2 + i;
        rowB[i] = seg * 16 + lrow;
        scB[i]  = (lchk ^ ((rowB[i] >> 1) & 3)) << 3;
        dstB[i] = &lB[seg * 512];
    }

    int roA[8], roB[4];
#pragma unroll
    for (int m = 0; m < 8; ++m)
        roA[m] = swz(wr * 128 + m * 16 + (lane & 15), lane >> 4);
#pragma unroll
    for (int n = 0; n < 4; ++n)
        roB[n] = swz(wc * 64 + n * 16 + (lane & 15), lane >> 4);

    const short* Ag = reinterpret_cast<const short*>(A);
    const short* Bg = reinterpret_cast<const short*>(B);

    f32x4 acc[8][4] = {};

    const int NT = K >> 5;
    for (int t = 0; t < NT; ++t) {
        const int k0 = t << 5;
#pragma unroll
        for (int i = 0; i < 4; ++i)
            GLOAD_LDS16(Ag + (size_t)(bm + rowA[i]) * K + k0 + scA[i], dstA[i]);
#pragma unroll
        for (int i = 0; i < 2; ++i)
            GLOAD_LDS16(Bg + (size_t)(bn + rowB[i]) * K + k0 + scB[i], dstB[i]);
        __syncthreads();   // vmcnt(0) drain; 32 MFMA below amortize it

        bf16x8 bfr[4];
#pragma unroll
        for (int n = 0; n < 4; ++n)
            bfr[n] = *reinterpret_cast<const bf16x8*>(&lB[roB[n]]);
#pragma unroll
        for (int m = 0; m < 8; ++m) {
            bf16x8 af = *reinterpret_cast<const bf16x8*>(&lA[roA[m]]);
#pragma unroll
            for (int n = 0; n < 4; ++n)
                acc[m][n] = __builtin_amdgcn_mfma_f32_16x16x32_bf16(
                    af, bfr[n], acc[m][n], 0, 0, 0);
        }
        __syncthreads();   // protect LDS from next tile's DMA
    }

    const int crow = (lane >> 4) * 4;
    const int ccol = lane & 15;
#pragma unroll
    for (int n = 0; n < 4; ++n) {
        const int col = bn + wc * 64 + n * 16 + ccol;
        const float bv = bias ? bias[col] : 0.f;
        if ((flags & 4) && col >= 1536) {
            const int hh = (col - 1536) >> 6;
            const int d  = (col - 1536) & 63;
#pragma unroll
            for (int m = 0; m < 8; ++m) {
                const int row0 = bm + wr * 128 + m * 16 + crow;
#pragma unroll
                for (int j = 0; j < 4; ++j) {
                    const int row = row0 + j;
                    const int ni = row >> 6, ll = row & 63;
                    Vout[(((size_t)ni * NHEAD + hh) << 12) + (d << 6) + ll] =
                        __float2bfloat16(acc[m][n][j] + bv);
                }
            }
        } else {
#pragma unroll
            for (int m = 0; m < 8; ++m) {
                const int row0 = bm + wr * 128 + m * 16 + crow;
#pragma unroll
                for (int j = 0; j < 4; ++j) {
                    float v = acc[m][n][j] + bv;
                    if (flags & 2) v = fmaxf(v, 0.f);
                    Cout[(size_t)(row0 + j) * ldC + col] = __float2bfloat16(v);
                }
            }
        }
    }
}

// ---------------------------------------------------------------------------
// MFMA attention: one wave per (n,h). qk: (8192,1536) bf16 Q|K rows;
// vt: (128,12,64,64) bf16 V^T; out: (8192,768) bf16.
__global__ __launch_bounds__(64) void attn_mfma_kernel(
    const __hip_bfloat16* __restrict__ qk,
    const __hip_bfloat16* __restrict__ vt,
    __hip_bfloat16* __restrict__ out)
{
    const int n = blockIdx.x, h = blockIdx.y;
    const int lane = threadIdx.x;
    const int lo = lane & 15, hi = lane >> 4;
    __shared__ short pl[64 * 72];

    const short* qg = reinterpret_cast<const short*>(qk) + (size_t)(n * 64) * 1536 + h * 64;

    f32x4 acc[4][4] = {};
#pragma unroll
    for (int ks = 0; ks < 2; ++ks) {
        const int kc = ks * 32 + hi * 8;
        bf16x8 af[4], bk[4];
#pragma unroll
        for (int m = 0; m < 4; ++m)
            af[m] = *reinterpret_cast<const bf16x8*>(qg + (size_t)(m * 16 + lo) * 1536 + kc);
#pragma unroll
        for (int nn = 0; nn < 4; ++nn)
            bk[nn] = *reinterpret_cast<const bf16x8*>(qg + 768 + (size_t)(nn * 16 + lo) * 1536 + kc);
#pragma unroll
        for (int m = 0; m < 4; ++m)
#pragma unroll
            for (int nn = 0; nn < 4; ++nn)
                acc[m][nn] = __builtin_amdgcn_mfma_f32_16x16x32_bf16(
                    af[m], bk[nn], acc[m][nn], 0, 0, 0);
    }

#pragma unroll
    for (int m = 0; m < 4; ++m) {
#pragma unroll
        for (int j = 0; j < 4; ++j) {
            float s0 = acc[m][0][j] * 0.125f;
            float s1 = acc[m][1][j] * 0.125f;
            float s2 = acc[m][2][j] * 0.125f;
            float s3 = acc[m][3][j] * 0.125f;
            float mx = fmaxf(fmaxf(s0, s1), fmaxf(s2, s3));
            mx = fmaxf(mx, __shfl_xor(mx, 1));
            mx = fmaxf(mx, __shfl_xor(mx, 2));
            mx = fmaxf(mx, __shfl_xor(mx, 4));
            mx = fmaxf(mx, __shfl_xor(mx, 8));
            float e0 = __expf(s0 - mx), e1 = __expf(s1 - mx);
            float e2 = __expf(s2 - mx), e3 = __expf(s3 - mx);
            float sm = e0 + e1 + e2 + e3;
            sm += __shfl_xor(sm, 1);
            sm += __shfl_xor(sm, 2);
            sm += __shfl_xor(sm, 4);
            sm += __shfl_xor(sm, 8);
            const float inv = 1.0f / sm;
            short* pr = &pl[(m * 16 + hi * 4 + j) * 72 + lo];
            pr[0]  = bf16s(e0 * inv);
            pr[16] = bf16s(e1 * inv);
            pr[32] = bf16s(e2 * inv);
            pr[48] = bf16s(e3 * inv);
        }
    }
    __syncthreads();

    const short* vg = reinterpret_cast<const short*>(vt) + ((size_t)(n * NHEAD + h) << 12);
    f32x4 o[4][4] = {};
#pragma unroll
    for (int ks = 0; ks < 2; ++ks) {
        const int kc = ks * 32 + hi * 8;
        bf16x8 pa[4], bv[4];
#pragma unroll
        for (int m = 0; m < 4; ++m)
            pa[m] = *reinterpret_cast<const bf16x8*>(&pl[(m * 16 + lo) * 72 + kc]);
#pragma unroll
        for (int nn = 0; nn < 4; ++nn)
            bv[nn] = *reinterpret_cast<const bf16x8*>(vg + (nn * 16 + lo) * 64 + kc);
#pragma unroll
        for (int m = 0; m < 4; ++m)
#pragma unroll
            for (int nn = 0; nn < 4; ++nn)
                o[m][nn] = __builtin_amdgcn_mfma_f32_16x16x32_bf16(
                    pa[m], bv[nn], o[m][nn], 0, 0, 0);
    }

#pragma unroll
    for (int m = 0; m < 4; ++m)
#pragma unroll
        for (int nn = 0; nn < 4; ++nn)
#pragma unroll
            for (int j = 0; j < 4; ++j)
                out[(size_t)(n * 64 + m * 16 + hi * 4 + j) * DD + h * 64 + nn * 16 + lo] =
                    __float2bfloat16(o[m][nn][j]);
}

// ---------------------------------------------------------------------------
// SAUTE part 1 (MFMA): P[row][u] = mask * (tok[row,:].v[b,u,:]).
__global__ __launch_bounds__(64) void saute_p_mfma_kernel(
    const __hip_bfloat16* __restrict__ Xb,
    const __hip_bfloat16* __restrict__ KV,
    const int* __restrict__ spk,
    __hip_bfloat16* __restrict__ P)
{
    const int lane = threadIdx.x;
    const int lo = lane & 15, hi = lane >> 4;
    const int row0 = blockIdx.x * 64;
    const int bt = row0 >> 6;
    const int b  = bt >> 5, t = bt & 31;

    const short* Ag = reinterpret_cast<const short*>(Xb) + (size_t)row0 * DD;
    const short* Bg = reinterpret_cast<const short*>(KV) + (size_t)(b * TT) * 1536 + 768;

    f32x4 acc[4][2] = {};
    for (int ks = 0; ks < 24; ++ks) {
        const int kc = ks * 32 + hi * 8;
        bf16x8 af[4], bv[2];
#pragma unroll
        for (int m = 0; m < 4; ++m)
            af[m] = *reinterpret_cast<const bf16x8*>(Ag + (size_t)(m * 16 + lo) * DD + kc);
#pragma unroll
        for (int nn = 0; nn < 2; ++nn)
            bv[nn] = *reinterpret_cast<const bf16x8*>(Bg + (size_t)(nn * 16 + lo) * 1536 + kc);
#pragma unroll
        for (int m = 0; m < 4; ++m)
#pragma unroll
            for (int nn = 0; nn < 2; ++nn)
                acc[m][nn] = __builtin_amdgcn_mfma_f32_16x16x32_bf16(
                    af[m], bv[nn], acc[m][nn], 0, 0, 0);
    }

    const int st = spk[bt];
#pragma unroll
    for (int nn = 0; nn < 2; ++nn) {
        const int u = nn * 16 + lo;
        const bool mk = (u <= t) && (spk[b * TT + u] == st);
#pragma unroll
        for (int m = 0; m < 4; ++m)
#pragma unroll
            for (int j = 0; j < 4; ++j) {
                const int row = row0 + m * 16 + hi * 4 + j;
                P[(size_t)row * 32 + u] =
                    mk ? __float2bfloat16(acc[m][nn][j]) : __float2bfloat16(0.f);
            }
    }
}

// ---------------------------------------------------------------------------
// SAUTE part 2: ctx = tok + P @ k, in place on bf16 Xb.
__global__ __launch_bounds__(256) void saute_ctx_kernel(
    __hip_bfloat16* __restrict__ Xb,
    const __hip_bfloat16* __restrict__ KV,
    const __hip_bfloat16* __restrict__ P)
{
    __shared__ unsigned kls[32 * 384];
    __shared__ float pls[8 * 32];
    const int row0 = blockIdx.x * 8;
    const int b = row0 >> 11;
    const int tid = threadIdx.x;

    const unsigned* k2 = reinterpret_cast<const unsigned*>(KV) + (size_t)(b * TT) * 768;
    for (int i = tid; i < 32 * 384; i += 256) {
        int u = i / 384, j = i - u * 384;
        kls[i] = k2[u * 768 + j];
    }
    pls[tid] = __bfloat162float(P[(size_t)row0 * 32 + tid]);
    __syncthreads();

    const int r = tid >> 5;
    const int l32 = tid & 31;
    unsigned* xrow = reinterpret_cast<unsigned*>(Xb + (size_t)(row0 + r) * DD);

    float2 acc[12];
#pragma unroll
    for (int c = 0; c < 12; ++c) {
        unsigned pk = xrow[l32 + 32 * c];
        acc[c].x = __uint_as_float(pk << 16);
        acc[c].y = __uint_as_float(pk & 0xffff0000u);
    }
    for (int u = 0; u < 32; ++u) {
        const float pv = pls[r * 32 + u];
        const unsigned* kr = &kls[u * 384];
#pragma unroll
        for (int c = 0; c < 12; ++c) {
            unsigned pk = kr[l32 + 32 * c];
            acc[c].x = fmaf(pv, __uint_as_float(pk << 16),          acc[c].x);
            acc[c].y = fmaf(pv, __uint_as_float(pk & 0xffff0000u), acc[c].y);
        }
    }
#pragma unroll
    for (int c = 0; c < 12; ++c)
        xrow[l32 + 32 * c] = pack_bf16(acc[c].x, acc[c].y);
}

// ---------------------------------------------------------------------------
// LayerNorm over bf16 residual: xb = bf16(LN(xb + y)); FINAL also writes fp32.
template<int FINAL>
__global__ __launch_bounds__(192) void add_ln_kernel(
    __hip_bfloat16* __restrict__ xb, const __hip_bfloat16* __restrict__ y,
    const float* __restrict__ g, const float* __restrict__ bb,
    float* __restrict__ xf)
{
    const int row = blockIdx.x;
    const int tid = threadIdx.x;
    __shared__ float red[3];
    __shared__ float stat[2];
    const size_t base = (size_t)row * DD + tid * 4;

    uint2 xv = *reinterpret_cast<const uint2*>(xb + base);
    uint2 yv = *reinterpret_cast<const uint2*>(y + base);
    float v[4];
    v[0] = __uint_as_float(xv.x << 16)         + __uint_as_float(yv.x << 16);
    v[1] = __uint_as_float(xv.x & 0xffff0000u) + __uint_as_float(yv.x & 0xffff0000u);
    v[2] = __uint_as_float(xv.y << 16)         + __uint_as_float(yv.y << 16);
    v[3] = __uint_as_float(xv.y & 0xffff0000u) + __uint_as_float(yv.y & 0xffff0000u);

    float s = v[0] + v[1] + v[2] + v[3];
#pragma unroll
    for (int off = 32; off > 0; off >>= 1) s += __shfl_down(s, off);
    if ((tid & 63) == 0) red[tid >> 6] = s;
    __syncthreads();
    if (tid == 0) stat[0] = (red[0] + red[1] + red[2]) * (1.0f / (float)DD);
    __syncthreads();
    const float mu = stat[0];

    float d[4];
    float q = 0.f;
#pragma unroll
    for (int i = 0; i < 4; ++i) { d[i] = v[i] - mu; q += d[i] * d[i]; }
    __syncthreads();
#pragma unroll
    for (int off = 32; off > 0; off >>= 1) q += __shfl_down(q, off);
    if ((tid & 63) == 0) red[tid >> 6] = q;
    __syncthreads();
    if (tid == 0) stat[1] = (red[0] + red[1] + red[2]) * (1.0f / (float)DD);
    __syncthreads();
    const float rstd = rsqrtf(stat[1] + 1e-5f);

    float o[4];
#pragma unroll
    for (int i = 0; i < 4; ++i)
        o[i] = d[i] * rstd * g[tid * 4 + i] + bb[tid * 4 + i];

    if (FINAL) {
        float4 f4 = make_float4(o[0], o[1], o[2], o[3]);
        *reinterpret_cast<float4*>(xf + base) = f4;
    } else {
        uint2 ov;
        ov.x = pack_bf16(o[0], o[1]);
        ov.y = pack_bf16(o[2], o[3]);
        *reinterpret_cast<uint2*>(xb + base) = ov;
    }
}

// ---------------------------------------------------------------------------
extern "C" void kernel_launch(void* const* d_in, const int* in_sizes, int n_in,
                              void* d_out, int out_size, void* d_ws, size_t ws_size,
                              hipStream_t stream) {
    (void)in_sizes; (void)n_in; (void)out_size; (void)ws_size;
    const float* te  = (const float*)d_in[0];
    const int*   spk = (const int*)  d_in[1];
    const float* Wq  = (const float*)d_in[2];
    const float* Wk  = (const float*)d_in[3];
    const float* Wv  = (const float*)d_in[4];
    const float* ipw = (const float*)d_in[5];
    const float* ipb = (const float*)d_in[6];
    const float* ow  = (const float*)d_in[7];
    const float* ob  = (const float*)d_in[8];
    const float* g1  = (const float*)d_in[9];
    const float* b1  = (const float*)d_in[10];
    const float* f1w = (const float*)d_in[11];
    const float* f1b = (const float*)d_in[12];
    const float* f2w = (const float*)d_in[13];
    const float* f2b = (const float*)d_in[14];
    const float* g2  = (const float*)d_in[15];
    const float* b2  = (const float*)d_in[16];

    float* Xout = (float*)d_out;

    // ws layout (bf16, all byte offsets multiples of 16)
    __hip_bfloat16* wsb   = (__hip_bfloat16*)d_ws;
    __hip_bfloat16* Wq_b  = wsb;                               //   589,824
    __hip_bfloat16* ipw_b = Wq_b  + 589824;                    // 3,538,944
    __hip_bfloat16* ow_b  = ipw_b + 3538944;                   // 1,179,648
    __hip_bfloat16* f1w_b = ow_b  + 1179648;                   // 3,145,728
    __hip_bfloat16* f2w_b = f1w_b + 3145728;                   // 3,145,728
    __hip_bfloat16* Xb    = f2w_b + 3145728;                   // 6,291,456 (bf16 residual)
    __hip_bfloat16* SCR   = Xb    + 6291456;                   // 18,874,368 combined region:
                                                               //   q|k (ld1536) + Vt; ff1 hidden
                                                               //   (ld2048) overruns into Vt AFTER
                                                               //   attn consumed it (safe);
                                                               //   Wkv_b aliases base pre-layer.
    __hip_bfloat16* Vt    = SCR   + 12582912;
    __hip_bfloat16* Wkv_b = SCR;                               // pre-layer alias
    __hip_bfloat16* Ab    = SCR   + 18874368;                  // 6,291,456
    __hip_bfloat16* Yb    = Ab    + 6291456;                   // 6,291,456
    __hip_bfloat16* KV    = Yb    + 6291456;                   // 196,608
    __hip_bfloat16* Pb    = KV    + 196608;                    // 262,144
    __hip_bfloat16* edu_b = Pb    + 262144;                    // 98,304

    // 1. te prep
    te_prep_kernel<<<(BTN * DD) / 256, 256, 0, stream>>>(te, Ab, edu_b);

    // 2. all weight casts in one launch
    CastArgs ca;
    ca.src[0] = Wq;  ca.dst[0] = Wq_b;
    ca.src[1] = ipw; ca.dst[1] = ipw_b;
    ca.src[2] = ow;  ca.dst[2] = ow_b;
    ca.src[3] = f1w; ca.dst[3] = f1w_b;
    ca.src[4] = f2w; ca.dst[4] = f2w_b;
    ca.src[5] = Wk;  ca.dst[5] = Wkv_b;
    ca.src[6] = Wv;  ca.dst[6] = Wkv_b + 589824;
    int quads[7] = {589824/4, 3538944/4, 1179648/4, 3145728/4, 3145728/4, 589824/4, 589824/4};
    int acc = 0;
    for (int i = 0; i < 7; ++i) { acc += quads[i]; ca.end[i] = acc; }
    cast_multi_kernel<<<(acc + 255) / 256, 256, 0, stream>>>(ca);

    // 3. k|v projection: KV = edu_b @ (Wk|Wv)^T
    gemm_bf16_kernel<1,0,0><<<dim3(1536/128, 1), 256, 0, stream>>>(
        edu_b, Wkv_b, nullptr, KV, nullptr, BTN, 1536, DD, 1536);

    // 4. tok = TE @ Wq^T  (bf16 out -> Xb)
    gemm_bf16_kernel<1,0,0><<<dim3(DD/128, ROWS/128), 256, 0, stream>>>(
        Ab, Wq_b, nullptr, Xb, nullptr, ROWS, DD, DD, DD);

    // 5. SAUTE
    saute_p_mfma_kernel<<<ROWS/64, 64, 0, stream>>>(Xb, KV, spk, Pb);
    saute_ctx_kernel<<<ROWS/8, 256, 0, stream>>>(Xb, KV, Pb);

    // 6. transformer layers
    for (int l = 0; l < NLAYERS; ++l) {
        const __hip_bfloat16* ipw_l = ipw_b + (size_t)l * 3 * DD * DD;
        const __hip_bfloat16* ow_l  = ow_b  + (size_t)l * DD * DD;
        const __hip_bfloat16* f1w_l = f1w_b + (size_t)l * DFF * DD;
        const __hip_bfloat16* f2w_l = f2w_b + (size_t)l * DD * DFF;

        // qkv (256x128 gload_lds): Q|K -> SCR (ld 1536), V -> Vt (transposed)
        gemm_256_kernel<<<dim3(3*DD/128, ROWS/256), 256, 0, stream>>>(
            Xb, ipw_l, ipb + (size_t)l * 3 * DD, SCR, Vt, ROWS, 3*DD, DD, 1536, 4);
        // attention -> Ab
        attn_mfma_kernel<<<dim3(BTN, NHEAD), 64, 0, stream>>>(SCR, Vt, Ab);
        // out proj -> Yb
        gemm_bf16_kernel<1,0,0><<<dim3(DD/128, ROWS/128), 256, 0, stream>>>(
            Ab, ow_l, ob + (size_t)l * DD, Yb, nullptr, ROWS, DD, DD, DD);
        // Xb = LN(Xb + Yb)
        add_ln_kernel<0><<<ROWS, 192, 0, stream>>>(
            Xb, Yb, g1 + (size_t)l * DD, b1 + (size_t)l * DD, nullptr);
        // H = relu(Xb @ ff1^T + b) -> SCR (256x128 gload_lds, ld 2048)
        gemm_256_kernel<<<dim3(DFF/128, ROWS/256), 256, 0, stream>>>(
            Xb, f1w_l, f1b + (size_t)l * DFF, SCR, nullptr, ROWS, DFF, DD, DFF, 2);
        // P = H @ ff2^T + b -> Yb, K=2048
        gemm_bf16_kernel<1,0,0><<<dim3(DD/128, ROWS/128), 256, 0, stream>>>(
            SCR, f2w_l, f2b + (size_t)l * DD, Yb, nullptr, ROWS, DD, DFF, DD);
        // Xb = LN(Xb + Yb); final layer writes fp32 d_out
        if (l == NLAYERS - 1)
            add_ln_kernel<1><<<ROWS, 192, 0, stream>>>(
                Xb, Yb, g2 + (size_t)l * DD, b2 + (size_t)l * DD, Xout);
        else
            add_ln_kernel<0><<<ROWS, 192, 0, stream>>>(
                Xb, Yb, g2 + (size_t)l * DD, b2 + (size_t)l * DD, nullptr);
    }
}

// Round 17
// 440.121 us; speedup vs baseline: 1.5497x; 1.3726x over previous
//
#include <hip/hip_runtime.h>
#include <hip/hip_bf16.h>

// Problem constants
#define BB 4
#define TT 32
#define LL 64
#define DD 768
#define NHEAD 12
#define DH 64
#define DFF 2048
#define NLAYERS 2
#define ROWS (BB*TT*LL)      // 8192
#define BTN  (BB*TT)         // 128

typedef __attribute__((ext_vector_type(8))) short bf16x8;
typedef __attribute__((ext_vector_type(4))) float f32x4;

// XOR swizzle for [R]x64-short LDS tiles (BK=64): row r, 16B chunk c (0..7).
__device__ __forceinline__ int swz64(int r, int c) {
    return r * 64 + ((c ^ (r & 7)) << 3);
}

// Bijective XCD-aware block remap (m204).
__device__ __forceinline__ int xcd_swizzle(int orig, int nwg) {
    const int q8 = nwg >> 3, r8 = nwg & 7;
    const int xcd = orig & 7, idx = orig >> 3;
    return (xcd < r8 ? xcd * (q8 + 1) : r8 * (q8 + 1) + (xcd - r8) * q8) + idx;
}

__device__ __forceinline__ unsigned pack_bf16(float a, float b) {
    __hip_bfloat16 h0 = __float2bfloat16(a);
    __hip_bfloat16 h1 = __float2bfloat16(b);
    return (unsigned)*reinterpret_cast<unsigned short*>(&h0) |
           ((unsigned)*reinterpret_cast<unsigned short*>(&h1) << 16);
}

__device__ __forceinline__ short bf16s(float a) {
    __hip_bfloat16 h = __float2bfloat16(a);
    return *reinterpret_cast<short*>(&h);
}

// ---------------------------------------------------------------------------
// Fused multi-tensor fp32 -> bf16 cast (7 segments, one launch).
struct CastArgs {
    const float* src[7];
    __hip_bfloat16* dst[7];
    int end[7];
};
__global__ __launch_bounds__(256) void cast_multi_kernel(CastArgs a)
{
    int q = blockIdx.x * 256 + threadIdx.x;
    if (q >= a.end[6]) return;
    int s = 0;
    while (q >= a.end[s]) ++s;
    int local = q - (s ? a.end[s - 1] : 0);
    float4 v = reinterpret_cast<const float4*>(a.src[s])[local];
    ushort4 o;
    __hip_bfloat16 h0 = __float2bfloat16(v.x);
    __hip_bfloat16 h1 = __float2bfloat16(v.y);
    __hip_bfloat16 h2 = __float2bfloat16(v.z);
    __hip_bfloat16 h3 = __float2bfloat16(v.w);
    o.x = *reinterpret_cast<unsigned short*>(&h0);
    o.y = *reinterpret_cast<unsigned short*>(&h1);
    o.z = *reinterpret_cast<unsigned short*>(&h2);
    o.w = *reinterpret_cast<unsigned short*>(&h3);
    reinterpret_cast<ushort4*>(a.dst[s])[local] = o;
}

// ---------------------------------------------------------------------------
// Fused: teb = bf16(te), edu_b = bf16(mean over L of te). One read of te.
__global__ __launch_bounds__(256) void te_prep_kernel(
    const float* __restrict__ te, __hip_bfloat16* __restrict__ teb,
    __hip_bfloat16* __restrict__ edu_b)
{
    int idx = blockIdx.x * 256 + threadIdx.x;
    int bt = idx / DD;
    int d  = idx - bt * DD;
    const float* p = te + ((size_t)bt * LL) * DD + d;
    __hip_bfloat16* q = teb + ((size_t)bt * LL) * DD + d;
    float s = 0.f;
#pragma unroll
    for (int l = 0; l < LL; ++l) {
        float v = p[(size_t)l * DD];
        s += v;
        q[(size_t)l * DD] = __float2bfloat16(v);
    }
    edu_b[idx] = __float2bfloat16(s * (1.0f / (float)LL));
}

// ---------------------------------------------------------------------------
// bf16 MFMA GEMM, 128x128 tile, BK=64, 256 thr (4 waves 2x2).
// Reg-staged double-buffered LDS (1 barrier per K-step), 8-chunk XOR
// swizzle, XCD-swizzled grid.
// Rationale (R16 post-mortem): R13's 55us is latency/serialization-bound
// (LDS-BW only ~17us of 55; ~1.7 blocks/CU). BK=64 halves barrier count
// (24->12 for K=768) and doubles the per-iteration compute window the
// global prefetch hides under. LDS 64KB dbuf -> 2 blocks/CU (= current
// effective co-residency).
// NOTE (R12/R16): 256-row tiles die on acc VGPRs. (R14): gload 2-barrier
// has no overlap. (R15): in-iteration direct-global A is latency-exposed.
template<int OUT_BF16, int RELU, int QKV>
__global__ __launch_bounds__(256) void gemm_bf16_kernel(
    const __hip_bfloat16* __restrict__ A,
    const __hip_bfloat16* __restrict__ B,
    const float* __restrict__ bias,
    void* __restrict__ Cout,
    __hip_bfloat16* __restrict__ Vout,
    int M, int N, int K, int ldC)
{
    __shared__ short lA[2][8192];   // 128 x 64
    __shared__ short lB[2][8192];
    const int tid  = threadIdx.x;
    const int lane = tid & 63;
    const int w    = tid >> 6;
    const int wr   = w >> 1, wc = w & 1;

    const int nbx = gridDim.x;
    const int wg = xcd_swizzle(blockIdx.y * nbx + blockIdx.x, nbx * gridDim.y);
    const int bm = (wg / nbx) * 128;
    const int bn = (wg % nbx) * 128;

    // staging: thread -> rows sr+32i (i=0..3), 16B chunk cw (0..7).
    // Linear global source; swizzled LDS write; same-swizzle LDS read.
    const int sr  = tid >> 3;        // 0..31
    const int cw  = tid & 7;         // 0..7
    const int sco = cw << 3;         // source elem offset
    int wox[4];
#pragma unroll
    for (int i = 0; i < 4; ++i)
        wox[i] = swz64(sr + 32 * i, cw);

    // read offsets: frag row r, k-sub-step ks (0,1) -> chunk ks*4 + hi
    const int lo = lane & 15, hi = lane >> 4;
    int roA[2][4], roB[2][4];
#pragma unroll
    for (int ks = 0; ks < 2; ++ks) {
#pragma unroll
        for (int m = 0; m < 4; ++m)
            roA[ks][m] = swz64(wr * 64 + m * 16 + lo, ks * 4 + hi);
#pragma unroll
        for (int n = 0; n < 4; ++n)
            roB[ks][n] = swz64(wc * 64 + n * 16 + lo, ks * 4 + hi);
    }

    const short* Ag = reinterpret_cast<const short*>(A);
    const short* Bg = reinterpret_cast<const short*>(B);

    f32x4 acc[4][4] = {};

    // prologue: tile 0 -> regs -> LDS buf0
    bf16x8 ra[4], rb[4];
#pragma unroll
    for (int i = 0; i < 4; ++i) {
        ra[i] = *reinterpret_cast<const bf16x8*>(Ag + (size_t)(bm + sr + 32 * i) * K + sco);
        rb[i] = *reinterpret_cast<const bf16x8*>(Bg + (size_t)(bn + sr + 32 * i) * K + sco);
    }
#pragma unroll
    for (int i = 0; i < 4; ++i) {
        *reinterpret_cast<bf16x8*>(&lA[0][wox[i]]) = ra[i];
        *reinterpret_cast<bf16x8*>(&lB[0][wox[i]]) = rb[i];
    }
    __syncthreads();

    const int NT = K >> 6;
    int cur = 0;
    for (int t = 0; t < NT; ++t) {
        const bool nx = (t + 1 < NT);
        if (nx) {  // prefetch next K-tile; latency hides under 32 MFMAs below
            const int kn = (t + 1) << 6;
#pragma unroll
            for (int i = 0; i < 4; ++i) {
                ra[i] = *reinterpret_cast<const bf16x8*>(Ag + (size_t)(bm + sr + 32 * i) * K + kn + sco);
                rb[i] = *reinterpret_cast<const bf16x8*>(Bg + (size_t)(bn + sr + 32 * i) * K + kn + sco);
            }
        }

#pragma unroll
        for (int ks = 0; ks < 2; ++ks) {
            bf16x8 af[4], bfr[4];
#pragma unroll
            for (int m = 0; m < 4; ++m)
                af[m] = *reinterpret_cast<const bf16x8*>(&lA[cur][roA[ks][m]]);
#pragma unroll
            for (int n = 0; n < 4; ++n)
                bfr[n] = *reinterpret_cast<const bf16x8*>(&lB[cur][roB[ks][n]]);
#pragma unroll
            for (int m = 0; m < 4; ++m)
#pragma unroll
                for (int n = 0; n < 4; ++n)
                    acc[m][n] = __builtin_amdgcn_mfma_f32_16x16x32_bf16(
                        af[m], bfr[n], acc[m][n], 0, 0, 0);
        }

        if (nx) {
#pragma unroll
            for (int i = 0; i < 4; ++i) {
                *reinterpret_cast<bf16x8*>(&lA[cur ^ 1][wox[i]]) = ra[i];
                *reinterpret_cast<bf16x8*>(&lB[cur ^ 1][wox[i]]) = rb[i];
            }
        }
        __syncthreads();
        cur ^= 1;
    }

    const int crow = (lane >> 4) * 4;
    const int ccol = lane & 15;
#pragma unroll
    for (int n = 0; n < 4; ++n) {
        const int col = bn + wc * 64 + n * 16 + ccol;
        const float bv = bias ? bias[col] : 0.f;
        if (QKV && col >= 1536) {
            const int hh = (col - 1536) >> 6;
            const int d  = (col - 1536) & 63;
#pragma unroll
            for (int m = 0; m < 4; ++m) {
                const int row0 = bm + wr * 64 + m * 16 + crow;
#pragma unroll
                for (int j = 0; j < 4; ++j) {
                    const int row = row0 + j;
                    const int ni = row >> 6, ll = row & 63;
                    Vout[(((size_t)ni * NHEAD + hh) << 12) + (d << 6) + ll] =
                        __float2bfloat16(acc[m][n][j] + bv);
                }
            }
        } else {
#pragma unroll
            for (int m = 0; m < 4; ++m) {
                const int row0 = bm + wr * 64 + m * 16 + crow;
#pragma unroll
                for (int j = 0; j < 4; ++j) {
                    float v = acc[m][n][j] + bv;
                    if (RELU) v = fmaxf(v, 0.f);
                    if (OUT_BF16)
                        reinterpret_cast<__hip_bfloat16*>(Cout)[(size_t)(row0 + j) * ldC + col] =
                            __float2bfloat16(v);
                    else
                        reinterpret_cast<float*>(Cout)[(size_t)(row0 + j) * ldC + col] = v;
                }
            }
        }
    }
}

// ---------------------------------------------------------------------------
// MFMA attention: one wave per (n,h). qk: (8192,1536) bf16 Q|K rows;
// vt: (128,12,64,64) bf16 V^T; out: (8192,768) bf16.
__global__ __launch_bounds__(64) void attn_mfma_kernel(
    const __hip_bfloat16* __restrict__ qk,
    const __hip_bfloat16* __restrict__ vt,
    __hip_bfloat16* __restrict__ out)
{
    const int n = blockIdx.x, h = blockIdx.y;
    const int lane = threadIdx.x;
    const int lo = lane & 15, hi = lane >> 4;
    __shared__ short pl[64 * 72];

    const short* qg = reinterpret_cast<const short*>(qk) + (size_t)(n * 64) * 1536 + h * 64;

    f32x4 acc[4][4] = {};
#pragma unroll
    for (int ks = 0; ks < 2; ++ks) {
        const int kc = ks * 32 + hi * 8;
        bf16x8 af[4], bk[4];
#pragma unroll
        for (int m = 0; m < 4; ++m)
            af[m] = *reinterpret_cast<const bf16x8*>(qg + (size_t)(m * 16 + lo) * 1536 + kc);
#pragma unroll
        for (int nn = 0; nn < 4; ++nn)
            bk[nn] = *reinterpret_cast<const bf16x8*>(qg + 768 + (size_t)(nn * 16 + lo) * 1536 + kc);
#pragma unroll
        for (int m = 0; m < 4; ++m)
#pragma unroll
            for (int nn = 0; nn < 4; ++nn)
                acc[m][nn] = __builtin_amdgcn_mfma_f32_16x16x32_bf16(
                    af[m], bk[nn], acc[m][nn], 0, 0, 0);
    }

#pragma unroll
    for (int m = 0; m < 4; ++m) {
#pragma unroll
        for (int j = 0; j < 4; ++j) {
            float s0 = acc[m][0][j] * 0.125f;
            float s1 = acc[m][1][j] * 0.125f;
            float s2 = acc[m][2][j] * 0.125f;
            float s3 = acc[m][3][j] * 0.125f;
            float mx = fmaxf(fmaxf(s0, s1), fmaxf(s2, s3));
            mx = fmaxf(mx, __shfl_xor(mx, 1));
            mx = fmaxf(mx, __shfl_xor(mx, 2));
            mx = fmaxf(mx, __shfl_xor(mx, 4));
            mx = fmaxf(mx, __shfl_xor(mx, 8));
            float e0 = __expf(s0 - mx), e1 = __expf(s1 - mx);
            float e2 = __expf(s2 - mx), e3 = __expf(s3 - mx);
            float sm = e0 + e1 + e2 + e3;
            sm += __shfl_xor(sm, 1);
            sm += __shfl_xor(sm, 2);
            sm += __shfl_xor(sm, 4);
            sm += __shfl_xor(sm, 8);
            const float inv = 1.0f / sm;
            short* pr = &pl[(m * 16 + hi * 4 + j) * 72 + lo];
            pr[0]  = bf16s(e0 * inv);
            pr[16] = bf16s(e1 * inv);
            pr[32] = bf16s(e2 * inv);
            pr[48] = bf16s(e3 * inv);
        }
    }
    __syncthreads();

    const short* vg = reinterpret_cast<const short*>(vt) + ((size_t)(n * NHEAD + h) << 12);
    f32x4 o[4][4] = {};
#pragma unroll
    for (int ks = 0; ks < 2; ++ks) {
        const int kc = ks * 32 + hi * 8;
        bf16x8 pa[4], bv[4];
#pragma unroll
        for (int m = 0; m < 4; ++m)
            pa[m] = *reinterpret_cast<const bf16x8*>(&pl[(m * 16 + lo) * 72 + kc]);
#pragma unroll
        for (int nn = 0; nn < 4; ++nn)
            bv[nn] = *reinterpret_cast<const bf16x8*>(vg + (nn * 16 + lo) * 64 + kc);
#pragma unroll
        for (int m = 0; m < 4; ++m)
#pragma unroll
            for (int nn = 0; nn < 4; ++nn)
                o[m][nn] = __builtin_amdgcn_mfma_f32_16x16x32_bf16(
                    pa[m], bv[nn], o[m][nn], 0, 0, 0);
    }

#pragma unroll
    for (int m = 0; m < 4; ++m)
#pragma unroll
        for (int nn = 0; nn < 4; ++nn)
#pragma unroll
            for (int j = 0; j < 4; ++j)
                out[(size_t)(n * 64 + m * 16 + hi * 4 + j) * DD + h * 64 + nn * 16 + lo] =
                    __float2bfloat16(o[m][nn][j]);
}

// ---------------------------------------------------------------------------
// SAUTE part 1 (MFMA): P[row][u] = mask * (tok[row,:].v[b,u,:]).
__global__ __launch_bounds__(64) void saute_p_mfma_kernel(
    const __hip_bfloat16* __restrict__ Xb,
    const __hip_bfloat16* __restrict__ KV,
    const int* __restrict__ spk,
    __hip_bfloat16* __restrict__ P)
{
    const int lane = threadIdx.x;
    const int lo = lane & 15, hi = lane >> 4;
    const int row0 = blockIdx.x * 64;
    const int bt = row0 >> 6;
    const int b  = bt >> 5, t = bt & 31;

    const short* Ag = reinterpret_cast<const short*>(Xb) + (size_t)row0 * DD;
    const short* Bg = reinterpret_cast<const short*>(KV) + (size_t)(b * TT) * 1536 + 768;

    f32x4 acc[4][2] = {};
    for (int ks = 0; ks < 24; ++ks) {
        const int kc = ks * 32 + hi * 8;
        bf16x8 af[4], bv[2];
#pragma unroll
        for (int m = 0; m < 4; ++m)
            af[m] = *reinterpret_cast<const bf16x8*>(Ag + (size_t)(m * 16 + lo) * DD + kc);
#pragma unroll
        for (int nn = 0; nn < 2; ++nn)
            bv[nn] = *reinterpret_cast<const bf16x8*>(Bg + (size_t)(nn * 16 + lo) * 1536 + kc);
#pragma unroll
        for (int m = 0; m < 4; ++m)
#pragma unroll
            for (int nn = 0; nn < 2; ++nn)
                acc[m][nn] = __builtin_amdgcn_mfma_f32_16x16x32_bf16(
                    af[m], bv[nn], acc[m][nn], 0, 0, 0);
    }

    const int st = spk[bt];
#pragma unroll
    for (int nn = 0; nn < 2; ++nn) {
        const int u = nn * 16 + lo;
        const bool mk = (u <= t) && (spk[b * TT + u] == st);
#pragma unroll
        for (int m = 0; m < 4; ++m)
#pragma unroll
            for (int j = 0; j < 4; ++j) {
                const int row = row0 + m * 16 + hi * 4 + j;
                P[(size_t)row * 32 + u] =
                    mk ? __float2bfloat16(acc[m][nn][j]) : __float2bfloat16(0.f);
            }
    }
}

// ---------------------------------------------------------------------------
// SAUTE part 2: ctx = tok + P @ k, in place on bf16 Xb.
__global__ __launch_bounds__(256) void saute_ctx_kernel(
    __hip_bfloat16* __restrict__ Xb,
    const __hip_bfloat16* __restrict__ KV,
    const __hip_bfloat16* __restrict__ P)
{
    __shared__ unsigned kls[32 * 384];
    __shared__ float pls[8 * 32];
    const int row0 = blockIdx.x * 8;
    const int b = row0 >> 11;
    const int tid = threadIdx.x;

    const unsigned* k2 = reinterpret_cast<const unsigned*>(KV) + (size_t)(b * TT) * 768;
    for (int i = tid; i < 32 * 384; i += 256) {
        int u = i / 384, j = i - u * 384;
        kls[i] = k2[u * 768 + j];
    }
    pls[tid] = __bfloat162float(P[(size_t)row0 * 32 + tid]);
    __syncthreads();

    const int r = tid >> 5;
    const int l32 = tid & 31;
    unsigned* xrow = reinterpret_cast<unsigned*>(Xb + (size_t)(row0 + r) * DD);

    float2 acc[12];
#pragma unroll
    for (int c = 0; c < 12; ++c) {
        unsigned pk = xrow[l32 + 32 * c];
        acc[c].x = __uint_as_float(pk << 16);
        acc[c].y = __uint_as_float(pk & 0xffff0000u);
    }
    for (int u = 0; u < 32; ++u) {
        const float pv = pls[r * 32 + u];
        const unsigned* kr = &kls[u * 384];
#pragma unroll
        for (int c = 0; c < 12; ++c) {
            unsigned pk = kr[l32 + 32 * c];
            acc[c].x = fmaf(pv, __uint_as_float(pk << 16),          acc[c].x);
            acc[c].y = fmaf(pv, __uint_as_float(pk & 0xffff0000u), acc[c].y);
        }
    }
#pragma unroll
    for (int c = 0; c < 12; ++c)
        xrow[l32 + 32 * c] = pack_bf16(acc[c].x, acc[c].y);
}

// ---------------------------------------------------------------------------
// LayerNorm over bf16 residual: xb = bf16(LN(xb + y)); FINAL also writes fp32.
template<int FINAL>
__global__ __launch_bounds__(192) void add_ln_kernel(
    __hip_bfloat16* __restrict__ xb, const __hip_bfloat16* __restrict__ y,
    const float* __restrict__ g, const float* __restrict__ bb,
    float* __restrict__ xf)
{
    const int row = blockIdx.x;
    const int tid = threadIdx.x;
    __shared__ float red[3];
    __shared__ float stat[2];
    const size_t base = (size_t)row * DD + tid * 4;

    uint2 xv = *reinterpret_cast<const uint2*>(xb + base);
    uint2 yv = *reinterpret_cast<const uint2*>(y + base);
    float v[4];
    v[0] = __uint_as_float(xv.x << 16)         + __uint_as_float(yv.x << 16);
    v[1] = __uint_as_float(xv.x & 0xffff0000u) + __uint_as_float(yv.x & 0xffff0000u);
    v[2] = __uint_as_float(xv.y << 16)         + __uint_as_float(yv.y << 16);
    v[3] = __uint_as_float(xv.y & 0xffff0000u) + __uint_as_float(yv.y & 0xffff0000u);

    float s = v[0] + v[1] + v[2] + v[3];
#pragma unroll
    for (int off = 32; off > 0; off >>= 1) s += __shfl_down(s, off);
    if ((tid & 63) == 0) red[tid >> 6] = s;
    __syncthreads();
    if (tid == 0) stat[0] = (red[0] + red[1] + red[2]) * (1.0f / (float)DD);
    __syncthreads();
    const float mu = stat[0];

    float d[4];
    float q = 0.f;
#pragma unroll
    for (int i = 0; i < 4; ++i) { d[i] = v[i] - mu; q += d[i] * d[i]; }
    __syncthreads();
#pragma unroll
    for (int off = 32; off > 0; off >>= 1) q += __shfl_down(q, off);
    if ((tid & 63) == 0) red[tid >> 6] = q;
    __syncthreads();
    if (tid == 0) stat[1] = (red[0] + red[1] + red[2]) * (1.0f / (float)DD);
    __syncthreads();
    const float rstd = rsqrtf(stat[1] + 1e-5f);

    float o[4];
#pragma unroll
    for (int i = 0; i < 4; ++i)
        o[i] = d[i] * rstd * g[tid * 4 + i] + bb[tid * 4 + i];

    if (FINAL) {
        float4 f4 = make_float4(o[0], o[1], o[2], o[3]);
        *reinterpret_cast<float4*>(xf + base) = f4;
    } else {
        uint2 ov;
        ov.x = pack_bf16(o[0], o[1]);
        ov.y = pack_bf16(o[2], o[3]);
        *reinterpret_cast<uint2*>(xb + base) = ov;
    }
}

// ---------------------------------------------------------------------------
extern "C" void kernel_launch(void* const* d_in, const int* in_sizes, int n_in,
                              void* d_out, int out_size, void* d_ws, size_t ws_size,
                              hipStream_t stream) {
    (void)in_sizes; (void)n_in; (void)out_size; (void)ws_size;
    const float* te  = (const float*)d_in[0];
    const int*   spk = (const int*)  d_in[1];
    const float* Wq  = (const float*)d_in[2];
    const float* Wk  = (const float*)d_in[3];
    const float* Wv  = (const float*)d_in[4];
    const float* ipw = (const float*)d_in[5];
    const float* ipb = (const float*)d_in[6];
    const float* ow  = (const float*)d_in[7];
    const float* ob  = (const float*)d_in[8];
    const float* g1  = (const float*)d_in[9];
    const float* b1  = (const float*)d_in[10];
    const float* f1w = (const float*)d_in[11];
    const float* f1b = (const float*)d_in[12];
    const float* f2w = (const float*)d_in[13];
    const float* f2b = (const float*)d_in[14];
    const float* g2  = (const float*)d_in[15];
    const float* b2  = (const float*)d_in[16];

    float* Xout = (float*)d_out;

    // ws layout (bf16, all byte offsets multiples of 16)
    __hip_bfloat16* wsb   = (__hip_bfloat16*)d_ws;
    __hip_bfloat16* Wq_b  = wsb;                               //   589,824
    __hip_bfloat16* ipw_b = Wq_b  + 589824;                    // 3,538,944
    __hip_bfloat16* ow_b  = ipw_b + 3538944;                   // 1,179,648
    __hip_bfloat16* f1w_b = ow_b  + 1179648;                   // 3,145,728
    __hip_bfloat16* f2w_b = f1w_b + 3145728;                   // 3,145,728
    __hip_bfloat16* Xb    = f2w_b + 3145728;                   // 6,291,456 (bf16 residual)
    __hip_bfloat16* SCR   = Xb    + 6291456;                   // 18,874,368 combined region:
                                                               //   q|k (ld1536) + Vt; ff1 hidden
                                                               //   (ld2048) overruns into Vt AFTER
                                                               //   attn consumed it (safe);
                                                               //   Wkv_b aliases base pre-layer.
    __hip_bfloat16* Vt    = SCR   + 12582912;
    __hip_bfloat16* Wkv_b = SCR;                               // pre-layer alias
    __hip_bfloat16* Ab    = SCR   + 18874368;                  // 6,291,456
    __hip_bfloat16* Yb    = Ab    + 6291456;                   // 6,291,456
    __hip_bfloat16* KV    = Yb    + 6291456;                   // 196,608
    __hip_bfloat16* Pb    = KV    + 196608;                    // 262,144
    __hip_bfloat16* edu_b = Pb    + 262144;                    // 98,304

    // 1. te prep
    te_prep_kernel<<<(BTN * DD) / 256, 256, 0, stream>>>(te, Ab, edu_b);

    // 2. all weight casts in one launch
    CastArgs ca;
    ca.src[0] = Wq;  ca.dst[0] = Wq_b;
    ca.src[1] = ipw; ca.dst[1] = ipw_b;
    ca.src[2] = ow;  ca.dst[2] = ow_b;
    ca.src[3] = f1w; ca.dst[3] = f1w_b;
    ca.src[4] = f2w; ca.dst[4] = f2w_b;
    ca.src[5] = Wk;  ca.dst[5] = Wkv_b;
    ca.src[6] = Wv;  ca.dst[6] = Wkv_b + 589824;
    int quads[7] = {589824/4, 3538944/4, 1179648/4, 3145728/4, 3145728/4, 589824/4, 589824/4};
    int acc = 0;
    for (int i = 0; i < 7; ++i) { acc += quads[i]; ca.end[i] = acc; }
    cast_multi_kernel<<<(acc + 255) / 256, 256, 0, stream>>>(ca);

    // 3. k|v projection: KV = edu_b @ (Wk|Wv)^T
    gemm_bf16_kernel<1,0,0><<<dim3(1536/128, 1), 256, 0, stream>>>(
        edu_b, Wkv_b, nullptr, KV, nullptr, BTN, 1536, DD, 1536);

    // 4. tok = TE @ Wq^T  (bf16 out -> Xb)
    gemm_bf16_kernel<1,0,0><<<dim3(DD/128, ROWS/128), 256, 0, stream>>>(
        Ab, Wq_b, nullptr, Xb, nullptr, ROWS, DD, DD, DD);

    // 5. SAUTE
    saute_p_mfma_kernel<<<ROWS/64, 64, 0, stream>>>(Xb, KV, spk, Pb);
    saute_ctx_kernel<<<ROWS/8, 256, 0, stream>>>(Xb, KV, Pb);

    // 6. transformer layers
    for (int l = 0; l < NLAYERS; ++l) {
        const __hip_bfloat16* ipw_l = ipw_b + (size_t)l * 3 * DD * DD;
        const __hip_bfloat16* ow_l  = ow_b  + (size_t)l * DD * DD;
        const __hip_bfloat16* f1w_l = f1w_b + (size_t)l * DFF * DD;
        const __hip_bfloat16* f2w_l = f2w_b + (size_t)l * DD * DFF;

        // qkv: Q|K -> SCR (ld 1536), V -> Vt (transposed per head)
        gemm_bf16_kernel<1,0,1><<<dim3(3*DD/128, ROWS/128), 256, 0, stream>>>(
            Xb, ipw_l, ipb + (size_t)l * 3 * DD, SCR, Vt, ROWS, 3*DD, DD, 1536);
        // attention -> Ab
        attn_mfma_kernel<<<dim3(BTN, NHEAD), 64, 0, stream>>>(SCR, Vt, Ab);
        // out proj -> Yb
        gemm_bf16_kernel<1,0,0><<<dim3(DD/128, ROWS/128), 256, 0, stream>>>(
            Ab, ow_l, ob + (size_t)l * DD, Yb, nullptr, ROWS, DD, DD, DD);
        // Xb = LN(Xb + Yb)
        add_ln_kernel<0><<<ROWS, 192, 0, stream>>>(
            Xb, Yb, g1 + (size_t)l * DD, b1 + (size_t)l * DD, nullptr);
        // H = relu(Xb @ ff1^T + b) -> SCR (bf16, ld 2048)
        gemm_bf16_kernel<1,1,0><<<dim3(DFF/128, ROWS/128), 256, 0, stream>>>(
            Xb, f1w_l, f1b + (size_t)l * DFF, SCR, nullptr, ROWS, DFF, DD, DFF);
        // P = H @ ff2^T + b -> Yb, K=2048
        gemm_bf16_kernel<1,0,0><<<dim3(DD/128, ROWS/128), 256, 0, stream>>>(
            SCR, f2w_l, f2b + (size_t)l * DD, Yb, nullptr, ROWS, DD, DFF, DD);
        // Xb = LN(Xb + Yb); final layer writes fp32 d_out
        if (l == NLAYERS - 1)
            add_ln_kernel<1><<<ROWS, 192, 0, stream>>>(
                Xb, Yb, g2 + (size_t)l * DD, b2 + (size_t)l * DD, Xout);
        else
            add_ln_kernel<0><<<ROWS, 192, 0, stream>>>(
                Xb, Yb, g2 + (size_t)l * DD, b2 + (size_t)l * DD, nullptr);
    }
}